// Round 5
// baseline (1258.102 us; speedup 1.0000x reference)
//
#include <hip/hip_runtime.h>
#include <hip/hip_bf16.h>

#define DIM 384
#define HEADS 12
#define NTOK 49
#define TOKENS 3137
#define M_ATTN 100352   // 32*64*49 window rows
#define M_FULL 100384   // 32*3137 token rows
#define M_PAD  100480   // 785*128
#define SCALEQ 0.17677669529663687f

typedef __attribute__((ext_vector_type(8))) short s8v;
typedef __attribute__((ext_vector_type(4))) float f4v;
typedef unsigned short u16;

__device__ __forceinline__ float b2f(int s) {
  union { unsigned u; float f; } c; c.u = ((unsigned)(s & 0xffff)) << 16; return c.f;
}
__device__ __forceinline__ u16 f2b(float f) {
  __hip_bfloat16 h = __float2bfloat16(f);
  return *reinterpret_cast<u16*>(&h);
}
__device__ __forceinline__ void gload16(const void* g, void* l) {
  __builtin_amdgcn_global_load_lds((const __attribute__((address_space(1))) void*)g,
                                   (__attribute__((address_space(3))) void*)l, 16, 0, 0);
}
__device__ __forceinline__ float gelu_f(float val) {
  // gelu(x) ~= x * sigmoid(1.5957691x + 0.0713548x^3), |err|<3e-3
  float u = __builtin_fmaf(0.0713548163f * val, val * val, 1.5957691216f * val);
  return val * __builtin_amdgcn_rcpf(1.0f + __expf(-u));
}

// ---------------- weight convert: f32 -> bf16, transposed to [N][K] ----------------
__global__ void k_convert(const float* __restrict__ qkv_w, const float* __restrict__ qkv_b,
                          const float* __restrict__ proj_w, const float* __restrict__ fc1_w,
                          const float* __restrict__ fc2_w,
                          u16* __restrict__ wt_qkv, float* __restrict__ qkvb_s,
                          u16* __restrict__ wt_proj, u16* __restrict__ wt_fc1,
                          u16* __restrict__ wt_fc2) {
  int i = blockIdx.x * 256 + threadIdx.x;
  if (i < 1152 * 384) { int n = i / 384, k = i % 384;
    float v = qkv_w[(size_t)k * 1152 + n]; if (n < 384) v *= SCALEQ; wt_qkv[i] = f2b(v); }
  if (i < 1152) qkvb_s[i] = qkv_b[i] * (i < 384 ? SCALEQ : 1.0f);
  if (i < 384 * 384) { int n = i / 384, k = i % 384; wt_proj[i] = f2b(proj_w[(size_t)k * 384 + n]); }
  if (i < 1536 * 384) { int n = i / 384, k = i % 384; wt_fc1[i] = f2b(fc1_w[(size_t)k * 1536 + n]); }
  if (i < 384 * 1536) { int n = i / 1536, k = i % 1536; wt_fc2[i] = f2b(fc2_w[(size_t)k * 384 + n]); }
}

// ---------------- ADD table: bias + shift mask per window class ----------------
__global__ void k_addtab(const float* __restrict__ rpb, float* __restrict__ ADD) {
  int idx = blockIdx.x * 256 + threadIdx.x;
  if (idx >= 4 * HEADS * NTOK * NTOK) return;
  int j = idx % NTOK, t = idx / NTOK;
  int i = t % NTOK; t /= NTOK;
  int h = t % HEADS; int cls = t / HEADS;
  int ii = i / 7, jj = i % 7, ji = j / 7, j2 = j % 7;
  int rpi = (ii - ji + 6) * 13 + (jj - j2 + 6);
  float v = rpb[rpi * HEADS + h];
  int rh = (cls & 2) ? (ii < 4 ? 1 : 2) : 0;
  int rw = (cls & 1) ? (jj < 4 ? 1 : 2) : 0;
  int sh = (cls & 2) ? (ji < 4 ? 1 : 2) : 0;
  int sw = (cls & 1) ? (j2 < 4 ? 1 : 2) : 0;
  if (rh != sh || rw != sw) v -= 100.0f;
  ADD[idx] = v;
}

// ---------------- LN1 + roll(-3,-3) + window partition -> xw bf16 ----------------
__global__ void k_ln1(const float* __restrict__ x, const float* __restrict__ g,
                      const float* __restrict__ b, u16* __restrict__ xw, int t0) {
  int wid = threadIdx.x >> 6, lane = threadIdx.x & 63;
  int t = t0 + blockIdx.x * 4 + wid;          // global window-row index
  int bi = t / 3136, rem = t % 3136;
  int win = rem / NTOK, n = rem % NTOK;
  int wh = win >> 3, ww = win & 7, ii = n / 7, jj = n % 7;
  int h = (wh * 7 + ii + 3) % 56;
  int w = (ww * 7 + jj + 3) % 56;
  const float* src = x + ((size_t)bi * TOKENS + 1 + h * 56 + w) * DIM;
  float v[6];
  #pragma unroll
  for (int e = 0; e < 6; e++) v[e] = src[lane + e * 64];
  float s = v[0] + v[1] + v[2] + v[3] + v[4] + v[5];
  #pragma unroll
  for (int m = 1; m < 64; m <<= 1) s += __shfl_xor(s, m);
  float mu = s * (1.0f / 384.0f);
  float q = 0.f;
  #pragma unroll
  for (int e = 0; e < 6; e++) { float d = v[e] - mu; q += d * d; }
  #pragma unroll
  for (int m = 1; m < 64; m <<= 1) q += __shfl_xor(q, m);
  float rstd = rsqrtf(q * (1.0f / 384.0f) + 1e-5f);
  u16* dst = xw + (size_t)(t - t0) * DIM;
  #pragma unroll
  for (int e = 0; e < 6; e++) {
    int c = lane + e * 64;
    dst[c] = f2b((v[e] - mu) * rstd * g[c] + b[c]);
  }
}

// ---------------- panel GEMM: full-K A-panel (128x384) staged contiguously in LDS.
// MODE 0: C[M][N] = A*Wa^T + ba -> bf16 (N=1152 qkv / N=384 proj)
// MODE 1: fused MLP: H = gelu(A*Wa^T+ba) chunk-wise; out = H*Wb^T + bb + A (resid), f32
template<int MODE>
__global__ __launch_bounds__(512, 1) void k_panel(
    const u16* __restrict__ A, const u16* __restrict__ Wa, const u16* __restrict__ Wb,
    const float* __restrict__ ba, const float* __restrict__ bb,
    u16* __restrict__ outb, float* __restrict__ outf, int N) {
  __shared__ __align__(16) u16 Xs[128 * 384];                 // 96 KB, 48 slots/row, XOR-swz
  __shared__ __align__(16) u16 Ws[128 * 64];                  // 16 KB, 8 slots/row, XOR-swz
  __shared__ __align__(16) u16 Hs[(MODE == 1) ? 128 * 128 : 16]; // 32 KB, 16 slots/row
  int tid = threadIdx.x;
  int wid = tid >> 6, lane = tid & 63, lo = lane & 15, hi = lane >> 4;
  int mh = (wid >> 2) * 64;      // wave m-base (2 groups)
  int nq = (wid & 3) * 32;       // wave n-base within 128-chunk (4 groups)
  int m0 = blockIdx.x * 128;
  const u16* Ap = A + (size_t)m0 * 384;

  // ---- stage full A-panel: flat contiguous 96 KB stream, source pre-swizzled ----
  #pragma unroll
  for (int i = 0; i < 12; i++) {
    int f = (wid * 12 + i) * 1024 + lane * 16;   // phys byte in Xs
    int row = f / 768;
    int slot = (f - row * 768) >> 4;             // phys 16B slot (0..47)
    gload16(Ap + row * 384 + ((slot ^ (row & 7)) << 3),
            (char*)Xs + (wid * 12 + i) * 1024);
  }

  // stage a 128x64 weight tile (rows rowbase.., cols kc..kc+64 of Wt[*][Krow])
  auto stageW = [&](const u16* Wt, int Krow, int rowbase, int kc) {
    #pragma unroll
    for (int i = 0; i < 2; i++) {
      int f = (wid * 2 + i) * 1024 + lane * 16;
      int row = f >> 7;
      int slot = (f >> 4) & 7;
      gload16(Wt + (size_t)(rowbase + row) * Krow + kc + ((slot ^ (row & 7)) << 3),
              (char*)Ws + (wid * 2 + i) * 1024);
    }
  };

  if (MODE == 0) {
    int nch = N >> 7;
    for (int ch = 0; ch < nch; ch++) {
      f4v acc[4][2];
      #pragma unroll
      for (int mi = 0; mi < 4; mi++)
        #pragma unroll
        for (int ni = 0; ni < 2; ni++) acc[mi][ni] = (f4v)(0.0f);
      for (int ks = 0; ks < 6; ks++) {
        __syncthreads();                         // prev Ws readers done
        stageW(Wa, 384, ch * 128, ks * 64);
        asm volatile("s_waitcnt vmcnt(0)" ::: "memory");
        __syncthreads();                         // tile visible
        #pragma unroll
        for (int kk = 0; kk < 2; kk++) {
          s8v a[4], b[2];
          #pragma unroll
          for (int mi = 0; mi < 4; mi++) {
            int m = mh + mi * 16 + lo; int s = (ks * 2 + kk) * 4 + hi;
            a[mi] = *(const s8v*)(Xs + m * 384 + ((s ^ (m & 7)) << 3));
          }
          #pragma unroll
          for (int ni = 0; ni < 2; ni++) {
            int nr = nq + ni * 16 + lo; int s = kk * 4 + hi;
            b[ni] = *(const s8v*)(Ws + nr * 64 + ((s ^ (nr & 7)) << 3));
          }
          #pragma unroll
          for (int mi = 0; mi < 4; mi++)
            #pragma unroll
            for (int ni = 0; ni < 2; ni++)
              acc[mi][ni] = __builtin_amdgcn_mfma_f32_16x16x32_bf16(a[mi], b[ni], acc[mi][ni], 0, 0, 0);
        }
      }
      #pragma unroll
      for (int mi = 0; mi < 4; mi++)
        #pragma unroll
        for (int ni = 0; ni < 2; ni++) {
          int gcol = ch * 128 + nq + ni * 16 + lo;
          float bv = ba[gcol];
          #pragma unroll
          for (int r = 0; r < 4; r++) {
            int grow = mh + mi * 16 + hi * 4 + r;
            outb[(size_t)(m0 + grow) * N + gcol] = f2b(acc[mi][ni][r] + bv);
          }
        }
    }
  } else {
    f4v acc2[3][4][2];
    #pragma unroll
    for (int g = 0; g < 3; g++)
      #pragma unroll
      for (int mi = 0; mi < 4; mi++)
        #pragma unroll
        for (int ni = 0; ni < 2; ni++) acc2[g][mi][ni] = (f4v)(0.0f);
    for (int ch = 0; ch < 12; ch++) {
      // ---- stage-1: acc1 = A * W1[ch-cols]^T ----
      f4v acc1[4][2];
      #pragma unroll
      for (int mi = 0; mi < 4; mi++)
        #pragma unroll
        for (int ni = 0; ni < 2; ni++) acc1[mi][ni] = (f4v)(0.0f);
      for (int ks = 0; ks < 6; ks++) {
        __syncthreads();
        stageW(Wa, 384, ch * 128, ks * 64);
        asm volatile("s_waitcnt vmcnt(0)" ::: "memory");
        __syncthreads();
        #pragma unroll
        for (int kk = 0; kk < 2; kk++) {
          s8v a[4], b[2];
          #pragma unroll
          for (int mi = 0; mi < 4; mi++) {
            int m = mh + mi * 16 + lo; int s = (ks * 2 + kk) * 4 + hi;
            a[mi] = *(const s8v*)(Xs + m * 384 + ((s ^ (m & 7)) << 3));
          }
          #pragma unroll
          for (int ni = 0; ni < 2; ni++) {
            int nr = nq + ni * 16 + lo; int s = kk * 4 + hi;
            b[ni] = *(const s8v*)(Ws + nr * 64 + ((s ^ (nr & 7)) << 3));
          }
          #pragma unroll
          for (int mi = 0; mi < 4; mi++)
            #pragma unroll
            for (int ni = 0; ni < 2; ni++)
              acc1[mi][ni] = __builtin_amdgcn_mfma_f32_16x16x32_bf16(a[mi], b[ni], acc1[mi][ni], 0, 0, 0);
        }
      }
      // ---- gelu -> Hs (swizzled scalar writes) ----
      #pragma unroll
      for (int mi = 0; mi < 4; mi++)
        #pragma unroll
        for (int ni = 0; ni < 2; ni++) {
          int col = nq + ni * 16 + lo;
          float bv = ba[ch * 128 + col];
          int sl = col >> 3, el = col & 7;
          #pragma unroll
          for (int r = 0; r < 4; r++) {
            int m = mh + mi * 16 + hi * 4 + r;
            Hs[m * 128 + ((sl ^ (m & 7)) << 3) + el] = f2b(gelu_f(acc1[mi][ni][r] + bv));
          }
        }
      // ---- stage-2: acc2 += H * W2[k2=ch-chunk]^T ----
      #pragma unroll
      for (int n2g = 0; n2g < 3; n2g++)
        for (int kt2 = 0; kt2 < 2; kt2++) {
          __syncthreads();                       // Hs visible / prev Ws readers done
          stageW(Wb, 1536, n2g * 128, ch * 128 + kt2 * 64);
          asm volatile("s_waitcnt vmcnt(0)" ::: "memory");
          __syncthreads();
          #pragma unroll
          for (int kk = 0; kk < 2; kk++) {
            s8v a[4], b[2];
            #pragma unroll
            for (int mi = 0; mi < 4; mi++) {
              int m = mh + mi * 16 + lo; int s = (kt2 * 2 + kk) * 4 + hi;
              a[mi] = *(const s8v*)(Hs + m * 128 + ((s ^ (m & 7)) << 3));
            }
            #pragma unroll
            for (int ni = 0; ni < 2; ni++) {
              int nr = nq + ni * 16 + lo; int s = kk * 4 + hi;
              b[ni] = *(const s8v*)(Ws + nr * 64 + ((s ^ (nr & 7)) << 3));
            }
            #pragma unroll
            for (int mi = 0; mi < 4; mi++)
              #pragma unroll
              for (int ni = 0; ni < 2; ni++)
                acc2[n2g][mi][ni] = __builtin_amdgcn_mfma_f32_16x16x32_bf16(a[mi], b[ni], acc2[n2g][mi][ni], 0, 0, 0);
          }
        }
    }
    // ---- epilogue: + bias + resid(from Xs) -> f32 out, row-guarded ----
    #pragma unroll
    for (int n2g = 0; n2g < 3; n2g++)
      #pragma unroll
      for (int mi = 0; mi < 4; mi++)
        #pragma unroll
        for (int ni = 0; ni < 2; ni++) {
          int gcol = n2g * 128 + nq + ni * 16 + lo;
          float bv = bb[gcol];
          int sl = gcol >> 3, el = gcol & 7;
          #pragma unroll
          for (int r = 0; r < 4; r++) {
            int ml = mh + mi * 16 + hi * 4 + r;
            int orow = m0 + ml;
            if (orow < M_FULL) {
              float res = b2f(Xs[ml * 384 + ((sl ^ (ml & 7)) << 3) + el]);
              outf[(size_t)orow * 384 + gcol] = acc2[n2g][mi][ni][r] + bv + res;
            }
          }
        }
  }
}

// ---------------- MFMA attention: one wave per window, 12 heads serial ----------------
__global__ __launch_bounds__(256) void k_attn2(const u16* __restrict__ qkv,
                                               const float* __restrict__ ADD,
                                               u16* __restrict__ ao, int win0) {
  __shared__ u16 PT[4][64][76];   // P transposed: PT[j][i] (+12 pad: 2-way-free banks)
  __shared__ u16 VT[4][32][76];   // V transposed: VT[d][j]
  int wid = threadIdx.x >> 6, lane = threadIdx.x & 63;
  int lo = lane & 15, hi = lane >> 4;
  int win_l = blockIdx.x * 4 + wid;
  int nw = (win0 + win_l) & 63;
  int wh = nw >> 3, ww = nw & 7;
  int cls = ((wh == 7) ? 2 : 0) + ((ww == 7) ? 1 : 0);
  size_t rowbase = (size_t)win_l * NTOK;
  u16 (*pt)[76] = PT[wid];
  u16 (*vt)[76] = VT[wid];

  int rcl[4];
  #pragma unroll
  for (int ti = 0; ti < 4; ti++) {
    int r = ti * 16 + lo;
    rcl[ti] = r < NTOK ? r : NTOK - 1;      // clamped fragment row
  }
  int jrow = lane < NTOK ? lane : NTOK - 1; // clamped V row for staging

  for (int h = 0; h < HEADS; h++) {
    s8v af[4], bf[4];
    #pragma unroll
    for (int ti = 0; ti < 4; ti++) {
      af[ti] = *(const s8v*)(qkv + (rowbase + rcl[ti]) * 1152 + h * 32 + hi * 8);
      bf[ti] = *(const s8v*)(qkv + (rowbase + rcl[ti]) * 1152 + 384 + h * 32 + hi * 8);
    }
    f4v st[4][4];
    #pragma unroll
    for (int mi = 0; mi < 4; mi++)
      #pragma unroll
      for (int ni = 0; ni < 4; ni++)
        st[mi][ni] = __builtin_amdgcn_mfma_f32_16x16x32_bf16(af[mi], bf[ni], (f4v)(0.0f), 0, 0, 0);

    {
      const u16* vsrc = qkv + (rowbase + jrow) * 1152 + 768 + h * 32;
      #pragma unroll
      for (int d0 = 0; d0 < 32; d0 += 8) {
        s8v v = *(const s8v*)(vsrc + d0);
        #pragma unroll
        for (int e = 0; e < 8; e++) vt[d0 + e][lane] = (u16)v[e];
      }
    }

    const float* addb = ADD + ((size_t)cls * HEADS + h) * (NTOK * NTOK);
    #pragma unroll
    for (int mi = 0; mi < 4; mi++)
      #pragma unroll
      for (int ni = 0; ni < 4; ni++) {
        int jj = ni * 16 + lo;
        #pragma unroll
        for (int r = 0; r < 4; r++) {
          int i = mi * 16 + hi * 4 + r;
          if (jj < NTOK) {
            int ic = i < NTOK ? i : NTOK - 1;
            st[mi][ni][r] += addb[ic * NTOK + jj];
          } else st[mi][ni][r] = -1e30f;
        }
      }

    float invl[4][4];
    #pragma unroll
    for (int mi = 0; mi < 4; mi++)
      #pragma unroll
      for (int r = 0; r < 4; r++) {
        float m = fmaxf(fmaxf(st[mi][0][r], st[mi][1][r]), fmaxf(st[mi][2][r], st[mi][3][r]));
        #pragma unroll
        for (int msk = 1; msk < 16; msk <<= 1) m = fmaxf(m, __shfl_xor(m, msk));
        float s = 0.f;
        #pragma unroll
        for (int ni = 0; ni < 4; ni++) {
          float p = __expf(st[mi][ni][r] - m);
          st[mi][ni][r] = p;
          s += p;
        }
        #pragma unroll
        for (int msk = 1; msk < 16; msk <<= 1) s += __shfl_xor(s, msk);
        invl[mi][r] = 1.0f / s;
      }

    #pragma unroll
    for (int ni = 0; ni < 4; ni++)
      #pragma unroll
      for (int mi = 0; mi < 4; mi++) {
        ushort4 pk;
        pk.x = f2b(st[mi][ni][0]); pk.y = f2b(st[mi][ni][1]);
        pk.z = f2b(st[mi][ni][2]); pk.w = f2b(st[mi][ni][3]);
        *(ushort4*)(&pt[ni * 16 + lo][mi * 16 + hi * 4]) = pk;
      }

    f4v ot[4][2];
    #pragma unroll
    for (int mi = 0; mi < 4; mi++)
      #pragma unroll
      for (int dt = 0; dt < 2; dt++) ot[mi][dt] = (f4v)(0.0f);
    #pragma unroll
    for (int kt = 0; kt < 2; kt++) {
      s8v pa[4], vb[2];
      #pragma unroll
      for (int mi = 0; mi < 4; mi++) {
        s8v p;
        #pragma unroll
        for (int e = 0; e < 8; e++) p[e] = (short)pt[kt * 32 + hi * 8 + e][mi * 16 + lo];
        pa[mi] = p;
      }
      #pragma unroll
      for (int dt = 0; dt < 2; dt++) {
        short4 a = *(const short4*)(&vt[dt * 16 + lo][kt * 32 + hi * 8]);
        short4 b = *(const short4*)(&vt[dt * 16 + lo][kt * 32 + hi * 8 + 4]);
        s8v v; v[0] = a.x; v[1] = a.y; v[2] = a.z; v[3] = a.w;
               v[4] = b.x; v[5] = b.y; v[6] = b.z; v[7] = b.w;
        vb[dt] = v;
      }
      #pragma unroll
      for (int mi = 0; mi < 4; mi++)
        #pragma unroll
        for (int dt = 0; dt < 2; dt++)
          ot[mi][dt] = __builtin_amdgcn_mfma_f32_16x16x32_bf16(pa[mi], vb[dt], ot[mi][dt], 0, 0, 0);
    }

    #pragma unroll
    for (int mi = 0; mi < 4; mi++)
      #pragma unroll
      for (int r = 0; r < 4; r++) {
        int i = mi * 16 + hi * 4 + r;
        if (i < NTOK) {
          u16* op = ao + (rowbase + i) * DIM + h * 32 + lo;
          op[0]  = f2b(ot[mi][0][r] * invl[mi][r]);
          op[16] = f2b(ot[mi][1][r] * invl[mi][r]);
        }
      }
  }
}

// ---------------- un-window + roll(+3,+3) + residual + LN2 -> x2 bf16 ----------------
__global__ void k_ln2(const float* __restrict__ x, const u16* __restrict__ proj,
                      const float* __restrict__ g, const float* __restrict__ b,
                      u16* __restrict__ x2b) {
  int wid = threadIdx.x >> 6, lane = threadIdx.x & 63;
  int r = blockIdx.x * 4 + wid;
  u16* dst = x2b + (size_t)r * DIM;
  if (r >= M_FULL) {
    u16 z = f2b(0.0f);
    #pragma unroll
    for (int e = 0; e < 6; e++) dst[lane + e * 64] = z;
    return;
  }
  int bi = r / TOKENS, tk = r % TOKENS;
  const float* xs = x + (size_t)r * DIM;
  float v[6];
  if (tk == 0) {
    #pragma unroll
    for (int e = 0; e < 6; e++) v[e] = xs[lane + e * 64];
  } else {
    int p = tk - 1, hh = p / 56, wp = p % 56;
    int a = (hh + 53) % 56, bw = (wp + 53) % 56;   // inverse roll by +3
    int wh = a / 7, ii = a % 7, w2 = bw / 7, jj = bw % 7;
    size_t prow = ((size_t)bi * 64 + wh * 8 + w2) * NTOK + ii * 7 + jj;
    const u16* ps = proj + prow * DIM;
    #pragma unroll
    for (int e = 0; e < 6; e++) v[e] = xs[lane + e * 64] + b2f(ps[lane + e * 64]);
  }
  float s = v[0] + v[1] + v[2] + v[3] + v[4] + v[5];
  #pragma unroll
  for (int m = 1; m < 64; m <<= 1) s += __shfl_xor(s, m);
  float mu = s * (1.0f / 384.0f);
  float q = 0.f;
  #pragma unroll
  for (int e = 0; e < 6; e++) { float d = v[e] - mu; q += d * d; }
  #pragma unroll
  for (int m = 1; m < 64; m <<= 1) q += __shfl_xor(q, m);
  float rstd = rsqrtf(q * (1.0f / 384.0f) + 1e-5f);
  #pragma unroll
  for (int e = 0; e < 6; e++) {
    int c = lane + e * 64;
    dst[c] = f2b((v[e] - mu) * rstd * g[c] + b[c]);
  }
}

extern "C" void kernel_launch(void* const* d_in, const int* in_sizes, int n_in,
                              void* d_out, int out_size, void* d_ws, size_t ws_size,
                              hipStream_t stream) {
  const float* x      = (const float*)d_in[0];
  const float* n1g    = (const float*)d_in[1];
  const float* n1b    = (const float*)d_in[2];
  const float* qkv_w  = (const float*)d_in[3];
  const float* qkv_b  = (const float*)d_in[4];
  const float* rpb    = (const float*)d_in[5];
  const float* proj_w = (const float*)d_in[6];
  const float* proj_b = (const float*)d_in[7];
  const float* n2g    = (const float*)d_in[8];
  const float* n2b    = (const float*)d_in[9];
  const float* fc1_w  = (const float*)d_in[10];
  const float* fc1_b  = (const float*)d_in[11];
  const float* fc2_w  = (const float*)d_in[12];
  const float* fc2_b  = (const float*)d_in[13];
  float* outp = (float*)d_out;

  auto al = [](size_t v) { return (v + 255) & ~(size_t)255; };
  size_t fixed = al(884736) + al(294912) + al(1179648) + al(1179648) + al(4608)
               + al(460992) + al((size_t)M_ATTN * 768) + al((size_t)M_PAD * 768);
  const int cands[5] = {1, 2, 4, 8, 16};
  int NC1 = 16;
  for (int ci = 0; ci < 5; ci++) {
    int c1 = cands[ci];
    size_t tot = fixed + al((size_t)(M_ATTN / c1) * 768) + al((size_t)(M_ATTN / c1) * 2304);
    if (tot <= ws_size) { NC1 = c1; break; }
  }
  char* p = (char*)d_ws;
  auto take = [&](size_t bytes) { char* r = p; p += al(bytes); return r; };
  u16* wt_qkv  = (u16*)take(884736);
  u16* wt_proj = (u16*)take(294912);
  u16* wt_fc1  = (u16*)take(1179648);
  u16* wt_fc2  = (u16*)take(1179648);
  float* qkvb_s = (float*)take(4608);
  float* ADDt   = (float*)take(460992);
  u16* PROJ = (u16*)take((size_t)M_ATTN * 768);
  u16* X2B  = (u16*)take((size_t)M_PAD * 768);
  int chunkM = M_ATTN / NC1;
  u16* XW   = (u16*)take((size_t)chunkM * 768);
  u16* QKV  = (u16*)take((size_t)chunkM * 2304);
  u16* AO = XW;   // alias: XW dead after QKV GEMM

  k_convert<<<2304, 256, 0, stream>>>(qkv_w, qkv_b, proj_w, fc1_w, fc2_w,
                                      wt_qkv, qkvb_s, wt_proj, wt_fc1, wt_fc2);
  k_addtab<<<451, 256, 0, stream>>>(rpb, ADDt);
  int chunkWin = chunkM / NTOK;
  for (int c = 0; c < NC1; c++) {
    int t0 = c * chunkM;
    k_ln1<<<chunkM / 4, 256, 0, stream>>>(x, n1g, n1b, XW, t0);
    k_panel<0><<<chunkM / 128, 512, 0, stream>>>(XW, wt_qkv, nullptr, qkvb_s, nullptr,
                                                 QKV, nullptr, 1152);
    k_attn2<<<chunkWin / 4, 256, 0, stream>>>(QKV, ADDt, AO, c * chunkWin);
    k_panel<0><<<chunkM / 128, 512, 0, stream>>>(AO, wt_proj, nullptr, proj_b, nullptr,
                                                 PROJ + (size_t)t0 * DIM, nullptr, 384);
  }
  k_ln2<<<M_PAD / 4, 256, 0, stream>>>(x, PROJ, n2g, n2b, X2B);
  k_panel<1><<<M_PAD / 128, 512, 0, stream>>>(X2B, wt_fc1, wt_fc2, fc1_b, fc2_b,
                                              nullptr, outp, 384);
}